// Round 5
// baseline (471.030 us; speedup 1.0000x reference)
//
#include <hip/hip_runtime.h>
#include <math.h>

// x (32,3,224,224) f32, thetas (32,17) f32 -> out (32,17,3,224,224) f32.
//
// Round 5 = Round 4 resubmit (bench infra failed twice; kernel never ran).
// Software-pipelined persistent blocks. Each block owns ~13 consecutive
// tiles (x 3 channels = ~39 items). One 46x49 LDS buffer.
// Per item: ds_write(prefetched regs) -> sync -> issue next item's global
// loads to regs -> compute+store current from LDS -> sync. Global-load
// latency hides under the compute phase instead of stalling at the barrier
// (R0-R3 all paid full load latency once per block behind __syncthreads).
// Channels of a tile are consecutive items -> bbox/sincos once per tile
// (fixes R3's 3x overhead); LSTR=49 odd -> conflict-free LDS reads
// (fixes R3's even-stride 4-way conflict). Per-pixel math identical to R2.
namespace {
constexpr int N_  = 32;
constexpr int S1_ = 17;
constexpr int C_  = 3;
constexpr int H_  = 224;
constexpr int W_  = 224;
constexpr int HW_ = H_ * W_;
constexpr int TILE = 32;                     // output tile (TILE x TILE)
constexpr int TPL  = W_ / TILE;              // 7 tiles per row
constexpr int TILES_PER_PLANE = TPL * TPL;   // 49
constexpr int NTILES = N_ * S1_ * TILES_PER_PLANE;  // 26656
constexpr int LH   = 46;                     // window rows
constexpr int LWX  = 48;                     // staged cols per row
constexpr int LSTR = 49;                     // LDS stride (odd: bank spread)
constexpr int NELEM = LH * LWX;              // 2208 staged floats per item
constexpr int THREADS = 256;
constexpr int SLOTS = (NELEM + THREADS - 1) / THREADS;  // 9 per thread
constexpr int NBLK  = 2048;                  // ~13 tiles per block
}

struct TileCtx {
  const float* img;   // x + n*C*HW
  int ns;
  int h0, w0;
  int rx0, ry0;
  int interior;
  float ct, st;
};

static __device__ inline TileCtx tile_coords(int tile,
                                             const float* __restrict__ x,
                                             const float* __restrict__ thetas) {
  TileCtx tc;
  const int ns = tile / TILES_PER_PLANE;
  const int t  = tile - ns * TILES_PER_PLANE;
  tc.ns = ns;
  const int n = ns / S1_;
  tc.h0 = (t / TPL) * TILE;
  tc.w0 = (t % TPL) * TILE;
  float st, ct;
  sincosf(thetas[ns], &st, &ct);
  tc.ct = ct; tc.st = st;
  // bbox of fx/fy over tile corners (linear map -> corners suffice).
  float fxmin = 1e30f, fymin = 1e30f;
#pragma unroll
  for (int cw = 0; cw < 2; ++cw) {
#pragma unroll
    for (int chh = 0; chh < 2; ++chh) {
      const float xs = ((tc.w0 + cw * (TILE - 1)) + 0.5f) * (2.0f / W_) - 1.0f;
      const float ys = ((tc.h0 + chh * (TILE - 1)) + 0.5f) * (2.0f / H_) - 1.0f;
      const float gx = ct * xs - st * ys;
      const float gy = st * xs + ct * ys;
      const float fx = ((gx + 1.0f) * W_ - 1.0f) * 0.5f;
      const float fy = ((gy + 1.0f) * H_ - 1.0f) * 0.5f;
      fxmin = fminf(fxmin, fx);
      fymin = fminf(fymin, fy);
    }
  }
  tc.rx0 = (int)floorf(fxmin - 0.1f);
  tc.ry0 = (int)floorf(fymin - 0.1f);
  tc.interior = (tc.rx0 >= 0) & (tc.ry0 >= 0) &
                (tc.rx0 + LWX <= W_) & (tc.ry0 + LH <= H_);
  tc.img = x + (size_t)n * (C_ * HW_);
  return tc;
}

// Issue this item's 9 global loads into registers (latency hidden by caller).
static __device__ inline void prefetch_item(const TileCtx& tc, int ch, int tid,
                                            float va[SLOTS]) {
  const float* __restrict__ p = tc.img + (size_t)ch * HW_;
  if (tc.interior) {
#pragma unroll
    for (int s = 0; s < SLOTS; ++s) {
      const int idx = tid + s * THREADS;
      float v = 0.0f;
      if (idx < NELEM) {
        const int r = idx / LWX;
        const int c = idx - r * LWX;
        v = p[(tc.ry0 + r) * W_ + (tc.rx0 + c)];
      }
      va[s] = v;
    }
  } else {
#pragma unroll
    for (int s = 0; s < SLOTS; ++s) {
      const int idx = tid + s * THREADS;
      float v = 0.0f;
      if (idx < NELEM) {
        const int r = idx / LWX;
        const int c = idx - r * LWX;
        const int gy = tc.ry0 + r;
        const int gx = tc.rx0 + c;
        const bool in = (gx >= 0) & (gx < W_) & (gy >= 0) & (gy < H_);
        const int off = (in ? gy : 0) * W_ + (in ? gx : 0);
        v = p[off] * (in ? 1.0f : 0.0f);
      }
      va[s] = v;
    }
  }
}

__global__ __launch_bounds__(THREADS) void rot_bilinear_pipe_kernel(
    const float* __restrict__ x,       // (N, C, H, W)
    const float* __restrict__ thetas,  // (N, S1)
    float* __restrict__ out) {         // (N, S1, C, H, W)
  __shared__ float lds[LH * LSTR];

  const int tid = threadIdx.x;
  const int b   = blockIdx.x;
  const int t0  = (int)((long)b * NTILES / NBLK);
  const int t1  = (int)((long)(b + 1) * NTILES / NBLK);
  const int nitems = (t1 - t0) * C_;

  // Compute-phase thread mapping: 4 consecutive px of one tile row.
  const int row    = tid >> 3;          // 0..31
  const int col    = (tid & 7) * 4;     // 0,4,...,28

  float va[SLOTS];                      // register prefetch buffer
  TileCtx tc_pre = tile_coords(t0, x, thetas);
  prefetch_item(tc_pre, 0, tid, va);
  TileCtx tc;                           // active (in-LDS) item's tile

  for (int i = 0; i < nitems; ++i) {
    __syncthreads();                    // prior item's LDS readers done
    // Stage prefetched registers into LDS.
#pragma unroll
    for (int s = 0; s < SLOTS; ++s) {
      const int idx = tid + s * THREADS;
      if (idx < NELEM) {
        const int r = idx / LWX;
        const int c = idx - r * LWX;
        lds[r * LSTR + c] = va[s];
      }
    }
    tc = tc_pre;
    const int ch = i - (i / C_) * C_;   // i % 3
    __syncthreads();                    // publish LDS

    // Issue NEXT item's loads now; they complete during compute below.
    if (i + 1 < nitems) {
      const int ch_n = (i + 1) - ((i + 1) / C_) * C_;
      if (ch_n == 0) tc_pre = tile_coords(t0 + (i + 1) / C_, x, thetas);
      prefetch_item(tc_pre, ch_n, tid, va);
    }

    // ---- Compute current item (channel ch of tile tc) from LDS. ----
    const int h = tc.h0 + row;
    const int w_base = tc.w0 + col;
    const float ys = (h + 0.5f) * (2.0f / H_) - 1.0f;
    const float xs0 = (w_base + 0.5f) * (2.0f / W_) - 1.0f;
    const float gx0 = tc.ct * xs0 - tc.st * ys;
    const float gy0 = tc.st * xs0 + tc.ct * ys;
    float fx = ((gx0 + 1.0f) * W_ - 1.0f) * 0.5f;  // reference-order px 0
    float fy = ((gy0 + 1.0f) * H_ - 1.0f) * 0.5f;
    // Per +1 output column: dfx = ct, dfy = st (grid scales cancel).

    float r0[4];
#pragma unroll
    for (int k = 0; k < 4; ++k) {
      const float fx0 = floorf(fx);
      const float fy0 = floorf(fy);
      const float wx1 = fx - fx0;
      const float wy1 = fy - fy0;
      const float wx0 = 1.0f - wx1;
      const float wy0 = 1.0f - wy1;
      const int lx = (int)fx0 - tc.rx0;   // in-window by bbox construction
      const int ly = (int)fy0 - tc.ry0;   // (outside-image taps read zeros)
      const int base = ly * LSTR + lx;
      const float w00 = wy0 * wx0, w01 = wy0 * wx1;
      const float w10 = wy1 * wx0, w11 = wy1 * wx1;
      r0[k] = w00 * lds[base]        + w01 * lds[base + 1] +
              w10 * lds[base + LSTR] + w11 * lds[base + LSTR + 1];
      fx += tc.ct;
      fy += tc.st;
    }

    float* __restrict__ o = out + (size_t)tc.ns * (C_ * HW_) +
                            (size_t)ch * HW_ + (size_t)h * W_ + w_base;
    *reinterpret_cast<float4*>(o) = make_float4(r0[0], r0[1], r0[2], r0[3]);
  }
}

extern "C" void kernel_launch(void* const* d_in, const int* in_sizes, int n_in,
                              void* d_out, int out_size, void* d_ws,
                              size_t ws_size, hipStream_t stream) {
  const float* x      = (const float*)d_in[0];
  const float* thetas = (const float*)d_in[1];
  float* out          = (float*)d_out;

  rot_bilinear_pipe_kernel<<<dim3(NBLK), dim3(THREADS), 0, stream>>>(
      x, thetas, out);
}